// Round 8
// baseline (365.100 us; speedup 1.0000x reference)
//
#include <hip/hip_runtime.h>

typedef unsigned short u16;
typedef __bf16 bf16x8 __attribute__((ext_vector_type(8)));
typedef float f32x4 __attribute__((ext_vector_type(4)));

// ---------- sizes ----------
#define Bsz 8192
#define Fdim 1024
#define Udim 512
#define Odim 3
#define Adim 6
#define Hdim 4

// ws element offsets (u16 elements)
#define OFF_FEAT   0
#define OFF_WAL    8388608     // W_lat = [W_al ; W_ol] contiguous (2048 x 1024)
#define OFF_WIN    10485760
#define OFF_WOUT   11272192
#define OFF_WAH    11534336
#define OFF_WOH    12058624
#define OFF_LAT    12845056    // B x 2048 : [agent_latent | opp0 | opp1 | opp2]
#define OFF_Q      29622272    // B x 512
#define OFF_KV     33816576    // 3 x B x 1024 : [k | v]
#define OFF_ATT    58982400    // B x 512
#define OFF_AGH    63176704    // B x 512
#define OFF_OPH    67371008    // 3 x B x 512
#define OFF_WOUTT  79953920    // 512 x 512 bf16 : W_out^T
#define OFF_WCOMB  80216064    // 512 x 512 bf16 : W_ah[:,512:] @ W_out
#define OFF_BAHC   80478208    // 512 f32 : b_ah + W_ah[:,512:] @ b_out
#define OFF_ZB     80479232    // 512 f32 : zeros

// d_out offsets (fp32 elements)
#define OUT_AP 0
#define OUT_AV 49152
#define OUT_OP 57344
#define OUT_OV 204800
#define OUT_IN 229376

__device__ __forceinline__ u16 f2bf(float f) {
  return __builtin_bit_cast(u16, (__bf16)f);
}
__device__ __forceinline__ float bf2f(u16 u) {
  return (float)__builtin_bit_cast(__bf16, u);
}

__device__ __forceinline__ void gload16(const u16* g, u16* s) {
  __builtin_amdgcn_global_load_lds(
      (const __attribute__((address_space(1))) unsigned int*)g,
      (__attribute__((address_space(3))) unsigned int*)s, 16, 0, 0);
}

// ---------- fp32 -> bf16 conversion + prep (woutT transpose, bahc, zb) ------
// blocks [0,12544): convert; [12544,12608): 64x64 transpose tiles of W_out;
// block 12608: zb = 0 and bahc = b_ah + WahR @ b_out (wave-per-row, coalesced).
#define CV_E0 2097152
#define CV_E1 2228224
#define CV_E2 2621440
#define CV_E3 2818048
#define CV_E4 2883584
#define CV_E5 3014656
#define CV_E6 3211264
__global__ __launch_bounds__(256) void convert_all(
    const float* __restrict__ f, const float* __restrict__ wal,
    const float* __restrict__ wol, const float* __restrict__ win,
    const float* __restrict__ wout, const float* __restrict__ wah,
    const float* __restrict__ woh, u16* __restrict__ dst,
    u16* __restrict__ woutT, float* __restrict__ bahc,
    const float* __restrict__ bout_f, const float* __restrict__ bah_f,
    float* __restrict__ zb) {
  if (blockIdx.x >= 12544) {
    if (blockIdx.x == 12608) {
      // zb
      zb[threadIdx.x] = 0.f;
      zb[threadIdx.x + 256] = 0.f;
      // bahc: wave w handles rows j = w, w+4, ... ; lanes split the 512 dim
      const int wave = threadIdx.x >> 6, lane = threadIdx.x & 63;
      for (int j = wave; j < 512; j += 4) {
        float s = 0.f;
#pragma unroll
        for (int c = 0; c < 8; ++c)
          s += wah[j * 1024 + 512 + c * 64 + lane] * bout_f[c * 64 + lane];
#pragma unroll
        for (int d = 32; d; d >>= 1) s += __shfl_xor(s, d, 64);
        if (lane == 0) bahc[j] = bah_f[j] + s;
      }
      return;
    }
    // transpose: woutT[u][v] = W_out[v][u]
    __shared__ float tile[64][65];
    const int bid = blockIdx.x - 12544;
    const int bx = bid & 7, byy = bid >> 3;
    const int v0 = byy * 64, u0 = bx * 64;
#pragma unroll
    for (int it = 0; it < 16; ++it) {
      int idx = it * 256 + threadIdx.x;
      int r = idx >> 6, c = idx & 63;
      tile[r][c] = wout[(v0 + r) * 512 + u0 + c];
    }
    __syncthreads();
#pragma unroll
    for (int it = 0; it < 16; ++it) {
      int idx = it * 256 + threadIdx.x;
      int r = idx >> 6, c = idx & 63;
      woutT[(u0 + r) * 512 + v0 + c] = f2bf(tile[c][r]);
    }
    return;
  }
  int i = blockIdx.x * 256 + threadIdx.x;
  const float* src;
  int base;
  if (i < CV_E0)      { src = f;    base = 0; }
  else if (i < CV_E1) { src = wal;  base = CV_E0; }
  else if (i < CV_E2) { src = wol;  base = CV_E1; }
  else if (i < CV_E3) { src = win;  base = CV_E2; }
  else if (i < CV_E4) { src = wout; base = CV_E3; }
  else if (i < CV_E5) { src = wah;  base = CV_E4; }
  else                { src = woh;  base = CV_E5; }
  float4 v = ((const float4*)src)[i - base];
  ushort4 o;
  o.x = f2bf(v.x); o.y = f2bf(v.y); o.z = f2bf(v.z); o.w = f2bf(v.w);
  ((ushort4*)dst)[i] = o;
}

// ============================================================================
// 256x256 8-phase bf16 GEMM for lat = elu(feat @ W_lat^T + b). Unchanged from
// round 2 (verified: FETCH near-ideal, 0 bank conflicts).
// ============================================================================
#define BAR() __builtin_amdgcn_s_barrier()
#define FENCE() asm volatile("" ::: "memory")
#define LGKM0() asm volatile("s_waitcnt lgkmcnt(0)" ::: "memory")
#define VMW(n) asm volatile("s_waitcnt vmcnt(" #n ")" ::: "memory")
#define MFMA(a, b, c) __builtin_amdgcn_mfma_f32_16x16x32_bf16(a, b, c, 0, 0, 0)
#define STAGE(MAT, SRC, LD, buf, ks, kb) do {                    \
    const u16* _s = (SRC) + (size_t)(kb) + (ks) * 32;            \
    gload16(_s, &MAT[buf][ks][wave * 512]);                      \
    gload16(_s + (size_t)128 * (LD), &MAT[buf][ks][4096 + wave * 512]); \
  } while (0)
#define RD_A(cur, ks, mh) do {                                   \
    _Pragma("unroll")                                            \
    for (int mi = 0; mi < 4; mi++)                               \
      a0[mi] = *(const bf16x8*)&As[cur][ks][aoff + (mh)*2048 + mi*512]; \
  } while (0)
#define RD_B(cur, ks) do {                                       \
    _Pragma("unroll")                                            \
    for (int ni = 0; ni < 4; ni++)                               \
      b0[ni] = *(const bf16x8*)&Bs[cur][ks][boff + ni*512];      \
  } while (0)
#define MFMA8(mh) do {                                           \
    __builtin_amdgcn_s_setprio(1);                               \
    _Pragma("unroll")                                            \
    for (int mi = 0; mi < 4; mi++) {                             \
      _Pragma("unroll")                                          \
      for (int ni = 0; ni < 4; ni++)                             \
        acc[(mh)*4+mi][ni] = MFMA(a0[mi], b0[ni], acc[(mh)*4+mi][ni]); \
    }                                                            \
    __builtin_amdgcn_s_setprio(0);                               \
  } while (0)

template <bool ELU>
__global__ __launch_bounds__(512, 2) void gemm256(
    const u16* __restrict__ A, const u16* __restrict__ Bw, u16* __restrict__ C,
    const float* __restrict__ bias1, const float* __restrict__ bias2,
    int bsplit, int K, int lda, int ldb, int ldc,
    long sAz, long sBz, long sCz, int sbz, float scale) {
  __shared__ __align__(16) u16 As[2][2][8192];
  __shared__ __align__(16) u16 Bs[2][2][8192];
  const int tid = threadIdx.x;
  const int wave = tid >> 6, lane = tid & 63;
  const int wr = wave >> 2, wc = wave & 3;

  const int nx = gridDim.x, ny = gridDim.y;
  const int nxy = nx * ny;
  const int nwg = nxy * gridDim.z;
  const int orig = blockIdx.x + nx * (blockIdx.y + ny * blockIdx.z);
  const int xcd = orig & 7;
  const int qd = nwg >> 3, rd = nwg & 7;
  const int wg = (xcd < rd ? xcd * (qd + 1) : rd * (qd + 1) + (xcd - rd) * qd)
               + (orig >> 3);
  const int z = wg / nxy;
  const int rem = wg - z * nxy;
  const int by = rem / nx;
  const int bx = rem - by * nx;

  A += (size_t)z * sAz;
  Bw += (size_t)z * sBz;
  C += (size_t)z * sCz;
  bias1 += (size_t)z * sbz;

  const int tM = by * 256, tN = bx * 256;

  const int srow = tid >> 2;
  const int schunk = ((tid & 3) ^ ((tid >> 3) & 3)) * 8;
  const u16* Asrc = A + (size_t)(tM + srow) * lda + schunk;
  const u16* Bsrc = Bw + (size_t)(tN + srow) * ldb + schunk;

  const int laneLo = lane & 15;
  const int pc8 = (((lane >> 4) ^ ((lane >> 1) & 3))) * 8;
  const int aoff = (wr * 128 + laneLo) * 32 + pc8;
  const int boff = (wc * 64 + laneLo) * 32 + pc8;

  f32x4 acc[8][4];
#pragma unroll
  for (int mi = 0; mi < 8; mi++)
#pragma unroll
    for (int ni = 0; ni < 4; ni++) acc[mi][ni] = (f32x4){0.f, 0.f, 0.f, 0.f};

  const int NT = K >> 6;

  STAGE(As, Asrc, lda, 0, 0, 0);
  STAGE(Bs, Bsrc, ldb, 0, 0, 0);
  STAGE(As, Asrc, lda, 0, 1, 0);
  STAGE(Bs, Bsrc, ldb, 0, 1, 0);
  VMW(4);
  BAR();

  int cur = 0;
  int kb = 64;
  bf16x8 a0[4], b0[4];
  for (int t = 0; t < NT; ++t) {
    const int nxt = cur ^ 1;
    const bool st = (t + 1 < NT);
    RD_B(cur, 0);
    RD_A(cur, 0, 0);
    if (st) STAGE(As, Asrc, lda, nxt, 0, kb);
    FENCE(); BAR(); LGKM0();
    MFMA8(0);
    FENCE(); BAR();
    RD_A(cur, 0, 1);
    if (st) STAGE(Bs, Bsrc, ldb, nxt, 0, kb);
    FENCE(); BAR(); LGKM0();
    MFMA8(1);
    if (st) { VMW(4); } else { VMW(0); }
    BAR();
    RD_B(cur, 1);
    RD_A(cur, 1, 0);
    if (st) STAGE(As, Asrc, lda, nxt, 1, kb);
    FENCE(); BAR(); LGKM0();
    MFMA8(0);
    FENCE(); BAR();
    RD_A(cur, 1, 1);
    if (st) STAGE(Bs, Bsrc, ldb, nxt, 1, kb);
    FENCE(); BAR(); LGKM0();
    MFMA8(1);
    if (st) { VMW(4); BAR(); }
    cur = nxt;
    kb += 64;
  }

#pragma unroll
  for (int ni = 0; ni < 4; ni++) {
    const int col = tN + wc * 64 + ni * 16 + laneLo;
    const float bv = (col < bsplit) ? bias1[col] : bias2[col - bsplit];
#pragma unroll
    for (int gm = 0; gm < 8; gm++) {
      const int row0 = tM + wr * 128 + gm * 16 + (lane >> 4) * 4;
#pragma unroll
      for (int r = 0; r < 4; r++) {
        float v = (acc[gm][ni][r] + bv) * scale;
        if (ELU) v = v > 0.f ? v : (__expf(v) - 1.f);
        C[(size_t)(row0 + r) * ldc + col] = f2bf(v);
      }
    }
  }
}
#undef STAGE
#undef RD_A
#undef RD_B
#undef MFMA8

// ============================================================================
// gemm_bt: r1/r2-verified 128xBN tile with symmetric split-A/split-B (agh).
// ============================================================================
template <int BN, bool ELU>
__global__ __launch_bounds__(256) void gemm_bt(
    const u16* __restrict__ A, const u16* __restrict__ A2,
    const u16* __restrict__ Bw, const u16* __restrict__ Bw2,
    int ksplit, int lda, int lda2, int ldb, int ldb2,
    u16* __restrict__ C, const float* __restrict__ bias,
    int K, int ldc, float scale) {
  constexpr int BM = 128, BK = 32;
  constexpr int NI = BN / 32;
  __shared__ __align__(16) u16 As[BM * BK];
  __shared__ __align__(16) u16 Bs[BN * BK];
  const int wave = threadIdx.x >> 6, lane = threadIdx.x & 63;

  const int nx = gridDim.x;
  const int nwg = nx * gridDim.y;
  const int orig = blockIdx.x + nx * blockIdx.y;
  const int xcd = orig & 7;
  const int qd = nwg >> 3, rd = nwg & 7;
  const int wg = (xcd < rd ? xcd * (qd + 1) : rd * (qd + 1) + (xcd - rd) * qd)
               + (orig >> 3);
  const int by = wg / nx, bx = wg - by * nx;
  const int tM = by * BM, tN = bx * BN;
  const int wr = wave >> 1, wc = wave & 1;

  f32x4 acc[4][NI];
#pragma unroll
  for (int i = 0; i < 4; i++)
#pragma unroll
    for (int j = 0; j < NI; j++) acc[i][j] = (f32x4){0.f, 0.f, 0.f, 0.f};

  const int srow = lane >> 2;
  const int scol = (lane & 3) * 8;

  for (int k0 = 0; k0 < K; k0 += BK) {
    const u16 *Ap, *Bp;
    int la, lb, kk;
    if (k0 < ksplit) { Ap = A;  la = lda;  Bp = Bw;  lb = ldb;  kk = k0; }
    else             { Ap = A2; la = lda2; Bp = Bw2; lb = ldb2; kk = k0 - ksplit; }
    __syncthreads();
#pragma unroll
    for (int i = 0; i < 2; ++i) {
      int r = wave * 32 + i * 16;
      gload16(Ap + (size_t)(tM + r + srow) * la + kk + scol, &As[r * BK]);
    }
#pragma unroll
    for (int i = 0; i < BN / 64; ++i) {
      int r = (wave * (BN / 64) + i) * 16;
      gload16(Bp + (size_t)(tN + r + srow) * lb + kk + scol, &Bs[r * BK]);
    }
    __syncthreads();
    bf16x8 af[4], bfr[NI];
#pragma unroll
    for (int mi = 0; mi < 4; mi++)
      af[mi] = *(const bf16x8*)&As[(wr * 64 + mi * 16 + (lane & 15)) * BK + (lane >> 4) * 8];
#pragma unroll
    for (int ni = 0; ni < NI; ni++)
      bfr[ni] = *(const bf16x8*)&Bs[(wc * (BN / 2) + ni * 16 + (lane & 15)) * BK + (lane >> 4) * 8];
#pragma unroll
    for (int mi = 0; mi < 4; mi++)
#pragma unroll
      for (int ni = 0; ni < NI; ni++)
        acc[mi][ni] = __builtin_amdgcn_mfma_f32_16x16x32_bf16(af[mi], bfr[ni], acc[mi][ni], 0, 0, 0);
  }

#pragma unroll
  for (int ni = 0; ni < NI; ni++) {
    int col = tN + wc * (BN / 2) + ni * 16 + (lane & 15);
    float bv = bias[col];
#pragma unroll
    for (int mi = 0; mi < 4; mi++) {
      int row0 = tM + wr * 64 + mi * 16 + (lane >> 4) * 4;
#pragma unroll
      for (int r = 0; r < 4; r++) {
        float v = (acc[mi][ni][r] + bv) * scale;
        if (ELU) v = v > 0.f ? v : (__expf(v) - 1.f);
        C[(size_t)(row0 + r) * ldc + col] = f2bf(v);
      }
    }
  }
}

// ============================================================================
// mega: exact-grid (2576 blocks, 1D) z-routed launch for all post-lat GEMMs.
//   wg [0,256)      : q     = (al @ Wq^T + bq)/sqrt(128)   4x64 tiles (N=512)
//   wg [256,1792)   : kv_o  = opp_o @ [Wk;Wv]^T + b        8x64x3      (N=1024)
//   wg [1792,2560)  : oph_o = elu(opp_o @ Woh_o^T + b)     4x64x3      (N=512)
//   wg [2560,2576)  : Wcomb = WahR @ WoutT                 4x4         (512x512)
// 2576 = 8*322 -> clean bijective XCD swizzle. No dead blocks (r7 had 1520).
// Inner loop identical to the r1/r7-verified 128x128 structure.
// ============================================================================
__global__ __launch_bounds__(256) void mega(
    const u16* __restrict__ lat, const u16* __restrict__ win,
    const u16* __restrict__ woh, const u16* __restrict__ wahb,
    const u16* __restrict__ woutT,
    u16* __restrict__ qb, u16* __restrict__ kvb, u16* __restrict__ oph,
    u16* __restrict__ wcomb,
    const float* __restrict__ b_in, const float* __restrict__ b_oh,
    const float* __restrict__ zb) {
  constexpr int BM = 128, BK = 32, BN = 128, NI = 4;
  __shared__ __align__(16) u16 As[BM * BK];
  __shared__ __align__(16) u16 Bs[BN * BK];
  const int wave = threadIdx.x >> 6, lane = threadIdx.x & 63;

  // bijective XCD swizzle; nwg = 2576 = 8*322
  const int orig = blockIdx.x;
  const int wg = (orig & 7) * 322 + (orig >> 3);

  // routing
  const u16 *A, *Bw;
  u16* C;
  const float* bias;
  int bx, by, ldc, lda = 2048;
  bool elu = false;
  float scale = 1.f;
  if (wg < 256) {
    bx = wg & 3; by = wg >> 2;
    A = lat; Bw = win; C = qb; bias = b_in;
    ldc = 512; scale = 0.08838834764831845f;
  } else if (wg < 1792) {
    int t = wg - 256, o = t >> 9, r = t & 511;
    bx = r & 7; by = r >> 3;
    A = lat + 512 * (o + 1); Bw = win + 262144;
    C = kvb + (size_t)o * 8388608; bias = b_in + 512;
    ldc = 1024;
  } else if (wg < 2560) {
    int t = wg - 1792, o = t >> 8, r = t & 255;
    bx = r & 3; by = r >> 2;
    A = lat + 512 * (o + 1); Bw = woh + (size_t)o * 262144;
    C = oph + (size_t)o * 4194304; bias = b_oh + o * 512;
    ldc = 512; elu = true;
  } else {
    int t = wg - 2560;
    bx = t & 3; by = t >> 2;
    A = wahb + 512; lda = 1024; Bw = woutT;
    C = wcomb; bias = zb;
    ldc = 512;
  }
  const int tM = by * BM, tN = bx * BN;
  const int wr = wave >> 1, wc = wave & 1;

  f32x4 acc[4][NI];
#pragma unroll
  for (int i = 0; i < 4; i++)
#pragma unroll
    for (int j = 0; j < NI; j++) acc[i][j] = (f32x4){0.f, 0.f, 0.f, 0.f};

  const int srow = lane >> 2;
  const int scol = (lane & 3) * 8;

  for (int k0 = 0; k0 < 512; k0 += BK) {
    __syncthreads();
#pragma unroll
    for (int i = 0; i < 2; ++i) {
      int r = wave * 32 + i * 16;
      gload16(A + (size_t)(tM + r + srow) * lda + k0 + scol, &As[r * BK]);
    }
#pragma unroll
    for (int i = 0; i < 2; ++i) {
      int r = (wave * 2 + i) * 16;
      gload16(Bw + (size_t)(tN + r + srow) * 512 + k0 + scol, &Bs[r * BK]);
    }
    __syncthreads();
    bf16x8 af[4], bfr[NI];
#pragma unroll
    for (int mi = 0; mi < 4; mi++)
      af[mi] = *(const bf16x8*)&As[(wr * 64 + mi * 16 + (lane & 15)) * BK + (lane >> 4) * 8];
#pragma unroll
    for (int ni = 0; ni < NI; ni++)
      bfr[ni] = *(const bf16x8*)&Bs[(wc * 64 + ni * 16 + (lane & 15)) * BK + (lane >> 4) * 8];
#pragma unroll
    for (int mi = 0; mi < 4; mi++)
#pragma unroll
      for (int ni = 0; ni < NI; ni++)
        acc[mi][ni] = __builtin_amdgcn_mfma_f32_16x16x32_bf16(af[mi], bfr[ni], acc[mi][ni], 0, 0, 0);
  }

#pragma unroll
  for (int ni = 0; ni < NI; ni++) {
    int col = tN + wc * 64 + ni * 16 + (lane & 15);
    float bv = bias[col];
#pragma unroll
    for (int mi = 0; mi < 4; mi++) {
      int row0 = tM + wr * 64 + mi * 16 + (lane >> 4) * 4;
#pragma unroll
      for (int r = 0; r < 4; r++) {
        float v = (acc[mi][ni][r] + bv) * scale;
        if (elu) v = v > 0.f ? v : (__expf(v) - 1.f);
        C[(size_t)(row0 + r) * ldc + col] = f2bf(v);
      }
    }
  }
}

// ---------- attention (r1-verified): scores/softmax over O=3, out + influ ----
__global__ __launch_bounds__(256) void attn_kernel(
    const u16* __restrict__ q, const u16* __restrict__ kv,
    u16* __restrict__ attn, float* __restrict__ influ) {
  const int wave = threadIdx.x >> 6, lane = threadIdx.x & 63;
  const int b = blockIdx.x * 4 + wave;
  const size_t qb = (size_t)b * 512;
  float wacc0 = 0.f, wacc1 = 0.f, wacc2 = 0.f;
#pragma unroll
  for (int h = 0; h < 4; ++h) {
    const int off = h * 128 + lane * 2;
    ushort2 qu = *(const ushort2*)(q + qb + off);
    float qx = bf2f(qu.x), qy = bf2f(qu.y);
    float s[3];
#pragma unroll
    for (int o = 0; o < 3; ++o) {
      ushort2 ku = *(const ushort2*)(kv + (size_t)o * (Bsz * 1024) + (size_t)b * 1024 + off);
      float p = qx * bf2f(ku.x) + qy * bf2f(ku.y);
#pragma unroll
      for (int d = 32; d; d >>= 1) p += __shfl_xor(p, d, 64);
      s[o] = p;
    }
    float m = fmaxf(s[0], fmaxf(s[1], s[2]));
    float e0 = __expf(s[0] - m), e1 = __expf(s[1] - m), e2 = __expf(s[2] - m);
    float inv = 1.f / (e0 + e1 + e2);
    float w0 = e0 * inv, w1 = e1 * inv, w2 = e2 * inv;
    wacc0 += w0; wacc1 += w1; wacc2 += w2;
    float ax = 0.f, ay = 0.f;
#pragma unroll
    for (int o = 0; o < 3; ++o) {
      float w = (o == 0) ? w0 : (o == 1) ? w1 : w2;
      ushort2 vu = *(const ushort2*)(kv + (size_t)o * (Bsz * 1024) + (size_t)b * 1024 + 512 + off);
      ax += w * bf2f(vu.x);
      ay += w * bf2f(vu.y);
    }
    ushort2 st; st.x = f2bf(ax); st.y = f2bf(ay);
    *(ushort2*)(attn + qb + off) = st;
  }
  if (lane == 0) {
    influ[b * 3 + 0] = wacc0 * 0.25f;
    influ[b * 3 + 1] = wacc1 * 0.25f;
    influ[b * 3 + 2] = wacc2 * 0.25f;
  }
}

// ---------- final heads (r0-verified): 28 length-512 dots per row ----------
__global__ __launch_bounds__(256) void heads_kernel(
    const u16* __restrict__ ah, const u16* __restrict__ oh,
    const float* __restrict__ Wap, const float* __restrict__ bap,
    const float* __restrict__ Wav, const float* __restrict__ bav,
    const float* __restrict__ Wop, const float* __restrict__ bop,
    const float* __restrict__ Wov, const float* __restrict__ bov,
    float* __restrict__ out) {
  __shared__ float sW[14336];
  for (int i = threadIdx.x; i < 14336; i += 256) {
    int s = i / 3584, rem = i - s * 3584;
    float v;
    if (s == 0) {
      v = (rem < 3072) ? Wap[rem] : Wav[rem - 3072];
    } else {
      int o = s - 1;
      v = (rem < 3072) ? Wop[o * 3072 + rem] : Wov[o * 512 + (rem - 3072)];
    }
    sW[i] = v;
  }
  __syncthreads();
  const int wave = threadIdx.x >> 6, lane = threadIdx.x & 63;
  const int kq = lane & 7, r = lane >> 3;
  const int b = blockIdx.x * 32 + wave * 8 + r;

  const u16* srcs[4] = {ah + (size_t)b * 512,
                        oh + (size_t)b * 512,
                        oh + (size_t)(Bsz + b) * 512,
                        oh + (size_t)(2 * Bsz + b) * 512};
  bf16x8 a[4][8];
#pragma unroll
  for (int s = 0; s < 4; s++)
#pragma unroll
    for (int c = 0; c < 8; c++)
      a[s][c] = *(const bf16x8*)(srcs[s] + c * 64 + kq * 8);

#pragma unroll
  for (int s = 0; s < 4; s++) {
#pragma unroll
    for (int p = 0; p < 7; p++) {
      const float* w = &sW[s * 3584 + p * 512 + kq * 8];
      float acc = 0.f;
#pragma unroll
      for (int c = 0; c < 8; c++) {
#pragma unroll
        for (int j = 0; j < 8; j++)
          acc += (float)a[s][c][j] * w[c * 64 + j];
      }
      acc += __shfl_xor(acc, 1, 64);
      acc += __shfl_xor(acc, 2, 64);
      acc += __shfl_xor(acc, 4, 64);
      if (kq == p) {
        if (s == 0) {
          if (p < 6) out[OUT_AP + b * 6 + p] = acc + bap[p];
          else       out[OUT_AV + b] = acc + bav[0];
        } else {
          int o = s - 1;
          if (p < 6) out[OUT_OP + b * 18 + o * 6 + p] = acc + bop[o * 6 + p];
          else       out[OUT_OV + b * 3 + o] = acc + bov[o];
        }
      }
    }
  }
}

extern "C" void kernel_launch(void* const* d_in, const int* in_sizes, int n_in,
                              void* d_out, int out_size, void* d_ws, size_t ws_size,
                              hipStream_t stream) {
  (void)in_sizes; (void)n_in; (void)out_size; (void)ws_size;
  const float* f     = (const float*)d_in[0];
  const float* W_al  = (const float*)d_in[1];
  const float* b_al  = (const float*)d_in[2];
  const float* W_in  = (const float*)d_in[3];
  const float* b_in  = (const float*)d_in[4];
  const float* W_out = (const float*)d_in[5];
  const float* b_out = (const float*)d_in[6];
  const float* W_ah  = (const float*)d_in[7];
  const float* b_ah  = (const float*)d_in[8];
  const float* W_ap  = (const float*)d_in[9];
  const float* b_ap  = (const float*)d_in[10];
  const float* W_av  = (const float*)d_in[11];
  const float* b_av  = (const float*)d_in[12];
  const float* W_ol  = (const float*)d_in[13];
  const float* b_ol  = (const float*)d_in[14];
  const float* W_oh  = (const float*)d_in[15];
  const float* b_oh  = (const float*)d_in[16];
  const float* W_op  = (const float*)d_in[17];
  const float* b_op  = (const float*)d_in[18];
  const float* W_ov  = (const float*)d_in[19];
  const float* b_ov  = (const float*)d_in[20];
  float* out = (float*)d_out;
  u16* ws = (u16*)d_ws;

  u16* feat  = ws + OFF_FEAT;
  u16* wal   = ws + OFF_WAL;    // [W_al ; W_ol] = W_lat (2048 x 1024)
  u16* win   = ws + OFF_WIN;
  u16* wahb  = ws + OFF_WAH;
  u16* woh   = ws + OFF_WOH;
  u16* lat   = ws + OFF_LAT;    // B x 2048
  u16* qb    = ws + OFF_Q;
  u16* kvb   = ws + OFF_KV;
  u16* att   = ws + OFF_ATT;
  u16* agh   = ws + OFF_AGH;
  u16* oph   = ws + OFF_OPH;
  u16* woutT = ws + OFF_WOUTT;
  u16* wcomb = ws + OFF_WCOMB;
  float* bahc = (float*)(ws + OFF_BAHC);
  float* zb   = (float*)(ws + OFF_ZB);

  // convert + woutT transpose + bahc + zb : one launch
  convert_all<<<12609, 256, 0, stream>>>(f, W_al, W_ol, W_in, W_out, W_ah,
                                         W_oh, ws, woutT, bahc, b_out, b_ah,
                                         zb);

  // lat = elu(feat @ W_lat^T + [b_al|b_ol]) : B x 2048
  gemm256<true><<<dim3(8, 32, 1), 512, 0, stream>>>(
      feat, wal, lat, b_al, b_ol, 512, 1024, 1024, 1024, 2048, 0, 0, 0, 0, 1.f);

  // q, kv(x3), opp_heads(x3), Wcomb : one exact-grid launch
  mega<<<2576, 256, 0, stream>>>(
      lat, win, woh, wahb, woutT, qb, kvb, oph, wcomb, b_in, b_oh, zb);

  attn_kernel<<<2048, 256, 0, stream>>>(qb, kvb, att, out + OUT_IN);

  // agent_head = elu([al | attn] @ [WahL ; Wcomb]^T + bahc)  (aout folded away)
  gemm_bt<64, true><<<dim3(8, 64), 256, 0, stream>>>(
      lat, att, wahb, wcomb, 512, 2048, 512, 1024, 512,
      agh, bahc, 1024, 512, 1.f);

  heads_kernel<<<256, 256, 0, stream>>>(agh, oph, W_ap, b_ap, W_av, b_av,
                                        W_op, b_op, W_ov, b_ov, out);
}

// Round 9
// 290.858 us; speedup vs baseline: 1.2552x; 1.2552x over previous
//
#include <hip/hip_runtime.h>

typedef unsigned short u16;
typedef __bf16 bf16x8 __attribute__((ext_vector_type(8)));
typedef float f32x4 __attribute__((ext_vector_type(4)));

// ---------- sizes ----------
#define Bsz 8192
#define Fdim 1024
#define Udim 512
#define Odim 3
#define Adim 6
#define Hdim 4

// ws element offsets (u16 elements)
#define OFF_FEAT   0
#define OFF_WAL    8388608     // W_lat = [W_al ; W_ol] contiguous (2048 x 1024)
#define OFF_WIN    10485760
#define OFF_WOUT   11272192
#define OFF_WAH    11534336
#define OFF_WOH    12058624
#define OFF_LAT    12845056    // B x 2048 : [agent_latent | opp0 | opp1 | opp2]
#define OFF_Q      29622272    // B x 512
#define OFF_KV     33816576    // 3 x B x 1024 : [k | v]
#define OFF_ATT    58982400    // B x 512
#define OFF_AGH    63176704    // B x 512
#define OFF_OPH    67371008    // 3 x B x 512
#define OFF_WOUTT  79953920    // 512 x 512 bf16 : W_out^T
#define OFF_WCOMB  80216064    // 512 x 512 bf16 : W_ah[:,512:] @ W_out
#define OFF_BAHC   80478208    // 512 f32 : b_ah + W_ah[:,512:] @ b_out
#define OFF_ZB     80479232    // 512 f32 : zeros

// d_out offsets (fp32 elements)
#define OUT_AP 0
#define OUT_AV 49152
#define OUT_OP 57344
#define OUT_OV 204800
#define OUT_IN 229376

__device__ __forceinline__ u16 f2bf(float f) {
  return __builtin_bit_cast(u16, (__bf16)f);
}
__device__ __forceinline__ float bf2f(u16 u) {
  return (float)__builtin_bit_cast(__bf16, u);
}

__device__ __forceinline__ void gload16(const u16* g, u16* s) {
  __builtin_amdgcn_global_load_lds(
      (const __attribute__((address_space(1))) unsigned int*)g,
      (__attribute__((address_space(3))) unsigned int*)s, 16, 0, 0);
}

// ---------- fp32 -> bf16 conversion + prep (woutT transpose, bahc, zb) ------
// blocks [0,12544): convert; [12544,12608): 64x64 transpose tiles of W_out
// (block 12544 also zeros zb); [12608,12672): bahc rows, 8 per block
// (r8 post-mortem: single-block bahc was an 85 us one-CU straggler).
#define CV_E0 2097152
#define CV_E1 2228224
#define CV_E2 2621440
#define CV_E3 2818048
#define CV_E4 2883584
#define CV_E5 3014656
#define CV_E6 3211264
__global__ __launch_bounds__(256) void convert_all(
    const float* __restrict__ f, const float* __restrict__ wal,
    const float* __restrict__ wol, const float* __restrict__ win,
    const float* __restrict__ wout, const float* __restrict__ wah,
    const float* __restrict__ woh, u16* __restrict__ dst,
    u16* __restrict__ woutT, float* __restrict__ bahc,
    const float* __restrict__ bout_f, const float* __restrict__ bah_f,
    float* __restrict__ zb) {
  if (blockIdx.x >= 12608) {
    // bahc: 64 blocks x 8 rows; wave handles 2 rows, lanes split the 512 dim
    const int wave = threadIdx.x >> 6, lane = threadIdx.x & 63;
    const int jbase = (blockIdx.x - 12608) * 8 + wave * 2;
#pragma unroll
    for (int t = 0; t < 2; ++t) {
      const int j = jbase + t;
      float s = 0.f;
#pragma unroll
      for (int c = 0; c < 8; ++c)
        s += wah[j * 1024 + 512 + c * 64 + lane] * bout_f[c * 64 + lane];
#pragma unroll
      for (int d = 32; d; d >>= 1) s += __shfl_xor(s, d, 64);
      if (lane == 0) bahc[j] = bah_f[j] + s;
    }
    return;
  }
  if (blockIdx.x >= 12544) {
    // transpose: woutT[u][v] = W_out[v][u]
    const int bid = blockIdx.x - 12544;
    if (bid == 0) {
      zb[threadIdx.x] = 0.f;
      zb[threadIdx.x + 256] = 0.f;
    }
    __shared__ float tile[64][65];
    const int bx = bid & 7, byy = bid >> 3;
    const int v0 = byy * 64, u0 = bx * 64;
#pragma unroll
    for (int it = 0; it < 16; ++it) {
      int idx = it * 256 + threadIdx.x;
      int r = idx >> 6, c = idx & 63;
      tile[r][c] = wout[(v0 + r) * 512 + u0 + c];
    }
    __syncthreads();
#pragma unroll
    for (int it = 0; it < 16; ++it) {
      int idx = it * 256 + threadIdx.x;
      int r = idx >> 6, c = idx & 63;
      woutT[(u0 + r) * 512 + v0 + c] = f2bf(tile[c][r]);
    }
    return;
  }
  int i = blockIdx.x * 256 + threadIdx.x;
  const float* src;
  int base;
  if (i < CV_E0)      { src = f;    base = 0; }
  else if (i < CV_E1) { src = wal;  base = CV_E0; }
  else if (i < CV_E2) { src = wol;  base = CV_E1; }
  else if (i < CV_E3) { src = win;  base = CV_E2; }
  else if (i < CV_E4) { src = wout; base = CV_E3; }
  else if (i < CV_E5) { src = wah;  base = CV_E4; }
  else                { src = woh;  base = CV_E5; }
  float4 v = ((const float4*)src)[i - base];
  ushort4 o;
  o.x = f2bf(v.x); o.y = f2bf(v.y); o.z = f2bf(v.z); o.w = f2bf(v.w);
  ((ushort4*)dst)[i] = o;
}

// ============================================================================
// 256x256 8-phase bf16 GEMM for lat = elu(feat @ W_lat^T + b). Unchanged from
// round 2 (verified: FETCH near-ideal, 0 bank conflicts).
// ============================================================================
#define BAR() __builtin_amdgcn_s_barrier()
#define FENCE() asm volatile("" ::: "memory")
#define LGKM0() asm volatile("s_waitcnt lgkmcnt(0)" ::: "memory")
#define VMW(n) asm volatile("s_waitcnt vmcnt(" #n ")" ::: "memory")
#define MFMA(a, b, c) __builtin_amdgcn_mfma_f32_16x16x32_bf16(a, b, c, 0, 0, 0)
#define STAGE(MAT, SRC, LD, buf, ks, kb) do {                    \
    const u16* _s = (SRC) + (size_t)(kb) + (ks) * 32;            \
    gload16(_s, &MAT[buf][ks][wave * 512]);                      \
    gload16(_s + (size_t)128 * (LD), &MAT[buf][ks][4096 + wave * 512]); \
  } while (0)
#define RD_A(cur, ks, mh) do {                                   \
    _Pragma("unroll")                                            \
    for (int mi = 0; mi < 4; mi++)                               \
      a0[mi] = *(const bf16x8*)&As[cur][ks][aoff + (mh)*2048 + mi*512]; \
  } while (0)
#define RD_B(cur, ks) do {                                       \
    _Pragma("unroll")                                            \
    for (int ni = 0; ni < 4; ni++)                               \
      b0[ni] = *(const bf16x8*)&Bs[cur][ks][boff + ni*512];      \
  } while (0)
#define MFMA8(mh) do {                                           \
    __builtin_amdgcn_s_setprio(1);                               \
    _Pragma("unroll")                                            \
    for (int mi = 0; mi < 4; mi++) {                             \
      _Pragma("unroll")                                          \
      for (int ni = 0; ni < 4; ni++)                             \
        acc[(mh)*4+mi][ni] = MFMA(a0[mi], b0[ni], acc[(mh)*4+mi][ni]); \
    }                                                            \
    __builtin_amdgcn_s_setprio(0);                               \
  } while (0)

template <bool ELU>
__global__ __launch_bounds__(512, 2) void gemm256(
    const u16* __restrict__ A, const u16* __restrict__ Bw, u16* __restrict__ C,
    const float* __restrict__ bias1, const float* __restrict__ bias2,
    int bsplit, int K, int lda, int ldb, int ldc,
    long sAz, long sBz, long sCz, int sbz, float scale) {
  __shared__ __align__(16) u16 As[2][2][8192];
  __shared__ __align__(16) u16 Bs[2][2][8192];
  const int tid = threadIdx.x;
  const int wave = tid >> 6, lane = tid & 63;
  const int wr = wave >> 2, wc = wave & 3;

  const int nx = gridDim.x, ny = gridDim.y;
  const int nxy = nx * ny;
  const int nwg = nxy * gridDim.z;
  const int orig = blockIdx.x + nx * (blockIdx.y + ny * blockIdx.z);
  const int xcd = orig & 7;
  const int qd = nwg >> 3, rd = nwg & 7;
  const int wg = (xcd < rd ? xcd * (qd + 1) : rd * (qd + 1) + (xcd - rd) * qd)
               + (orig >> 3);
  const int z = wg / nxy;
  const int rem = wg - z * nxy;
  const int by = rem / nx;
  const int bx = rem - by * nx;

  A += (size_t)z * sAz;
  Bw += (size_t)z * sBz;
  C += (size_t)z * sCz;
  bias1 += (size_t)z * sbz;

  const int tM = by * 256, tN = bx * 256;

  const int srow = tid >> 2;
  const int schunk = ((tid & 3) ^ ((tid >> 3) & 3)) * 8;
  const u16* Asrc = A + (size_t)(tM + srow) * lda + schunk;
  const u16* Bsrc = Bw + (size_t)(tN + srow) * ldb + schunk;

  const int laneLo = lane & 15;
  const int pc8 = (((lane >> 4) ^ ((lane >> 1) & 3))) * 8;
  const int aoff = (wr * 128 + laneLo) * 32 + pc8;
  const int boff = (wc * 64 + laneLo) * 32 + pc8;

  f32x4 acc[8][4];
#pragma unroll
  for (int mi = 0; mi < 8; mi++)
#pragma unroll
    for (int ni = 0; ni < 4; ni++) acc[mi][ni] = (f32x4){0.f, 0.f, 0.f, 0.f};

  const int NT = K >> 6;

  STAGE(As, Asrc, lda, 0, 0, 0);
  STAGE(Bs, Bsrc, ldb, 0, 0, 0);
  STAGE(As, Asrc, lda, 0, 1, 0);
  STAGE(Bs, Bsrc, ldb, 0, 1, 0);
  VMW(4);
  BAR();

  int cur = 0;
  int kb = 64;
  bf16x8 a0[4], b0[4];
  for (int t = 0; t < NT; ++t) {
    const int nxt = cur ^ 1;
    const bool st = (t + 1 < NT);
    RD_B(cur, 0);
    RD_A(cur, 0, 0);
    if (st) STAGE(As, Asrc, lda, nxt, 0, kb);
    FENCE(); BAR(); LGKM0();
    MFMA8(0);
    FENCE(); BAR();
    RD_A(cur, 0, 1);
    if (st) STAGE(Bs, Bsrc, ldb, nxt, 0, kb);
    FENCE(); BAR(); LGKM0();
    MFMA8(1);
    if (st) { VMW(4); } else { VMW(0); }
    BAR();
    RD_B(cur, 1);
    RD_A(cur, 1, 0);
    if (st) STAGE(As, Asrc, lda, nxt, 1, kb);
    FENCE(); BAR(); LGKM0();
    MFMA8(0);
    FENCE(); BAR();
    RD_A(cur, 1, 1);
    if (st) STAGE(Bs, Bsrc, ldb, nxt, 1, kb);
    FENCE(); BAR(); LGKM0();
    MFMA8(1);
    if (st) { VMW(4); BAR(); }
    cur = nxt;
    kb += 64;
  }

#pragma unroll
  for (int ni = 0; ni < 4; ni++) {
    const int col = tN + wc * 64 + ni * 16 + laneLo;
    const float bv = (col < bsplit) ? bias1[col] : bias2[col - bsplit];
#pragma unroll
    for (int gm = 0; gm < 8; gm++) {
      const int row0 = tM + wr * 128 + gm * 16 + (lane >> 4) * 4;
#pragma unroll
      for (int r = 0; r < 4; r++) {
        float v = (acc[gm][ni][r] + bv) * scale;
        if (ELU) v = v > 0.f ? v : (__expf(v) - 1.f);
        C[(size_t)(row0 + r) * ldc + col] = f2bf(v);
      }
    }
  }
}
#undef STAGE
#undef RD_A
#undef RD_B
#undef MFMA8

// ============================================================================
// gemm_bt: r1/r2-verified 128xBN tile with symmetric split-A/split-B (agh).
// ============================================================================
template <int BN, bool ELU>
__global__ __launch_bounds__(256) void gemm_bt(
    const u16* __restrict__ A, const u16* __restrict__ A2,
    const u16* __restrict__ Bw, const u16* __restrict__ Bw2,
    int ksplit, int lda, int lda2, int ldb, int ldb2,
    u16* __restrict__ C, const float* __restrict__ bias,
    int K, int ldc, float scale) {
  constexpr int BM = 128, BK = 32;
  constexpr int NI = BN / 32;
  __shared__ __align__(16) u16 As[BM * BK];
  __shared__ __align__(16) u16 Bs[BN * BK];
  const int wave = threadIdx.x >> 6, lane = threadIdx.x & 63;

  const int nx = gridDim.x;
  const int nwg = nx * gridDim.y;
  const int orig = blockIdx.x + nx * blockIdx.y;
  const int xcd = orig & 7;
  const int qd = nwg >> 3, rd = nwg & 7;
  const int wg = (xcd < rd ? xcd * (qd + 1) : rd * (qd + 1) + (xcd - rd) * qd)
               + (orig >> 3);
  const int by = wg / nx, bx = wg - by * nx;
  const int tM = by * BM, tN = bx * BN;
  const int wr = wave >> 1, wc = wave & 1;

  f32x4 acc[4][NI];
#pragma unroll
  for (int i = 0; i < 4; i++)
#pragma unroll
    for (int j = 0; j < NI; j++) acc[i][j] = (f32x4){0.f, 0.f, 0.f, 0.f};

  const int srow = lane >> 2;
  const int scol = (lane & 3) * 8;

  for (int k0 = 0; k0 < K; k0 += BK) {
    const u16 *Ap, *Bp;
    int la, lb, kk;
    if (k0 < ksplit) { Ap = A;  la = lda;  Bp = Bw;  lb = ldb;  kk = k0; }
    else             { Ap = A2; la = lda2; Bp = Bw2; lb = ldb2; kk = k0 - ksplit; }
    __syncthreads();
#pragma unroll
    for (int i = 0; i < 2; ++i) {
      int r = wave * 32 + i * 16;
      gload16(Ap + (size_t)(tM + r + srow) * la + kk + scol, &As[r * BK]);
    }
#pragma unroll
    for (int i = 0; i < BN / 64; ++i) {
      int r = (wave * (BN / 64) + i) * 16;
      gload16(Bp + (size_t)(tN + r + srow) * lb + kk + scol, &Bs[r * BK]);
    }
    __syncthreads();
    bf16x8 af[4], bfr[NI];
#pragma unroll
    for (int mi = 0; mi < 4; mi++)
      af[mi] = *(const bf16x8*)&As[(wr * 64 + mi * 16 + (lane & 15)) * BK + (lane >> 4) * 8];
#pragma unroll
    for (int ni = 0; ni < NI; ni++)
      bfr[ni] = *(const bf16x8*)&Bs[(wc * (BN / 2) + ni * 16 + (lane & 15)) * BK + (lane >> 4) * 8];
#pragma unroll
    for (int mi = 0; mi < 4; mi++)
#pragma unroll
      for (int ni = 0; ni < NI; ni++)
        acc[mi][ni] = __builtin_amdgcn_mfma_f32_16x16x32_bf16(af[mi], bfr[ni], acc[mi][ni], 0, 0, 0);
  }

#pragma unroll
  for (int ni = 0; ni < NI; ni++) {
    int col = tN + wc * (BN / 2) + ni * 16 + (lane & 15);
    float bv = bias[col];
#pragma unroll
    for (int mi = 0; mi < 4; mi++) {
      int row0 = tM + wr * 64 + mi * 16 + (lane >> 4) * 4;
#pragma unroll
      for (int r = 0; r < 4; r++) {
        float v = (acc[mi][ni][r] + bv) * scale;
        if (ELU) v = v > 0.f ? v : (__expf(v) - 1.f);
        C[(size_t)(row0 + r) * ldc + col] = f2bf(v);
      }
    }
  }
}

// ============================================================================
// mega: exact-grid (2576 blocks, 1D) z-routed launch for all post-lat GEMMs.
//   wg [0,256)      : q     = (al @ Wq^T + bq)/sqrt(128)   4x64 tiles (N=512)
//   wg [256,1792)   : kv_o  = opp_o @ [Wk;Wv]^T + b        8x64x3      (N=1024)
//   wg [1792,2560)  : oph_o = elu(opp_o @ Woh_o^T + b)     4x64x3      (N=512)
//   wg [2560,2576)  : Wcomb = WahR @ WoutT                 4x4         (512x512)
// 2576 = 8*322 -> clean bijective XCD swizzle. No dead blocks.
// ============================================================================
__global__ __launch_bounds__(256) void mega(
    const u16* __restrict__ lat, const u16* __restrict__ win,
    const u16* __restrict__ woh, const u16* __restrict__ wahb,
    const u16* __restrict__ woutT,
    u16* __restrict__ qb, u16* __restrict__ kvb, u16* __restrict__ oph,
    u16* __restrict__ wcomb,
    const float* __restrict__ b_in, const float* __restrict__ b_oh,
    const float* __restrict__ zb) {
  constexpr int BM = 128, BK = 32, BN = 128, NI = 4;
  __shared__ __align__(16) u16 As[BM * BK];
  __shared__ __align__(16) u16 Bs[BN * BK];
  const int wave = threadIdx.x >> 6, lane = threadIdx.x & 63;

  // bijective XCD swizzle; nwg = 2576 = 8*322
  const int orig = blockIdx.x;
  const int wg = (orig & 7) * 322 + (orig >> 3);

  // routing
  const u16 *A, *Bw;
  u16* C;
  const float* bias;
  int bx, by, ldc, lda = 2048;
  bool elu = false;
  float scale = 1.f;
  if (wg < 256) {
    bx = wg & 3; by = wg >> 2;
    A = lat; Bw = win; C = qb; bias = b_in;
    ldc = 512; scale = 0.08838834764831845f;
  } else if (wg < 1792) {
    int t = wg - 256, o = t >> 9, r = t & 511;
    bx = r & 7; by = r >> 3;
    A = lat + 512 * (o + 1); Bw = win + 262144;
    C = kvb + (size_t)o * 8388608; bias = b_in + 512;
    ldc = 1024;
  } else if (wg < 2560) {
    int t = wg - 1792, o = t >> 8, r = t & 255;
    bx = r & 3; by = r >> 2;
    A = lat + 512 * (o + 1); Bw = woh + (size_t)o * 262144;
    C = oph + (size_t)o * 4194304; bias = b_oh + o * 512;
    ldc = 512; elu = true;
  } else {
    int t = wg - 2560;
    bx = t & 3; by = t >> 2;
    A = wahb + 512; lda = 1024; Bw = woutT;
    C = wcomb; bias = zb;
    ldc = 512;
  }
  const int tM = by * BM, tN = bx * BN;
  const int wr = wave >> 1, wc = wave & 1;

  f32x4 acc[4][NI];
#pragma unroll
  for (int i = 0; i < 4; i++)
#pragma unroll
    for (int j = 0; j < NI; j++) acc[i][j] = (f32x4){0.f, 0.f, 0.f, 0.f};

  const int srow = lane >> 2;
  const int scol = (lane & 3) * 8;

  for (int k0 = 0; k0 < 512; k0 += BK) {
    __syncthreads();
#pragma unroll
    for (int i = 0; i < 2; ++i) {
      int r = wave * 32 + i * 16;
      gload16(A + (size_t)(tM + r + srow) * lda + k0 + scol, &As[r * BK]);
    }
#pragma unroll
    for (int i = 0; i < 2; ++i) {
      int r = (wave * 2 + i) * 16;
      gload16(Bw + (size_t)(tN + r + srow) * 512 + k0 + scol, &Bs[r * BK]);
    }
    __syncthreads();
    bf16x8 af[4], bfr[NI];
#pragma unroll
    for (int mi = 0; mi < 4; mi++)
      af[mi] = *(const bf16x8*)&As[(wr * 64 + mi * 16 + (lane & 15)) * BK + (lane >> 4) * 8];
#pragma unroll
    for (int ni = 0; ni < NI; ni++)
      bfr[ni] = *(const bf16x8*)&Bs[(wc * 64 + ni * 16 + (lane & 15)) * BK + (lane >> 4) * 8];
#pragma unroll
    for (int mi = 0; mi < 4; mi++)
#pragma unroll
      for (int ni = 0; ni < NI; ni++)
        acc[mi][ni] = __builtin_amdgcn_mfma_f32_16x16x32_bf16(af[mi], bfr[ni], acc[mi][ni], 0, 0, 0);
  }

#pragma unroll
  for (int ni = 0; ni < NI; ni++) {
    int col = tN + wc * 64 + ni * 16 + (lane & 15);
    float bv = bias[col];
#pragma unroll
    for (int mi = 0; mi < 4; mi++) {
      int row0 = tM + wr * 64 + mi * 16 + (lane >> 4) * 4;
#pragma unroll
      for (int r = 0; r < 4; r++) {
        float v = (acc[mi][ni][r] + bv) * scale;
        if (elu) v = v > 0.f ? v : (__expf(v) - 1.f);
        C[(size_t)(row0 + r) * ldc + col] = f2bf(v);
      }
    }
  }
}

// ---------- attention (r1-verified): scores/softmax over O=3, out + influ ----
__global__ __launch_bounds__(256) void attn_kernel(
    const u16* __restrict__ q, const u16* __restrict__ kv,
    u16* __restrict__ attn, float* __restrict__ influ) {
  const int wave = threadIdx.x >> 6, lane = threadIdx.x & 63;
  const int b = blockIdx.x * 4 + wave;
  const size_t qb = (size_t)b * 512;
  float wacc0 = 0.f, wacc1 = 0.f, wacc2 = 0.f;
#pragma unroll
  for (int h = 0; h < 4; ++h) {
    const int off = h * 128 + lane * 2;
    ushort2 qu = *(const ushort2*)(q + qb + off);
    float qx = bf2f(qu.x), qy = bf2f(qu.y);
    float s[3];
#pragma unroll
    for (int o = 0; o < 3; ++o) {
      ushort2 ku = *(const ushort2*)(kv + (size_t)o * (Bsz * 1024) + (size_t)b * 1024 + off);
      float p = qx * bf2f(ku.x) + qy * bf2f(ku.y);
#pragma unroll
      for (int d = 32; d; d >>= 1) p += __shfl_xor(p, d, 64);
      s[o] = p;
    }
    float m = fmaxf(s[0], fmaxf(s[1], s[2]));
    float e0 = __expf(s[0] - m), e1 = __expf(s[1] - m), e2 = __expf(s[2] - m);
    float inv = 1.f / (e0 + e1 + e2);
    float w0 = e0 * inv, w1 = e1 * inv, w2 = e2 * inv;
    wacc0 += w0; wacc1 += w1; wacc2 += w2;
    float ax = 0.f, ay = 0.f;
#pragma unroll
    for (int o = 0; o < 3; ++o) {
      float w = (o == 0) ? w0 : (o == 1) ? w1 : w2;
      ushort2 vu = *(const ushort2*)(kv + (size_t)o * (Bsz * 1024) + (size_t)b * 1024 + 512 + off);
      ax += w * bf2f(vu.x);
      ay += w * bf2f(vu.y);
    }
    ushort2 st; st.x = f2bf(ax); st.y = f2bf(ay);
    *(ushort2*)(attn + qb + off) = st;
  }
  if (lane == 0) {
    influ[b * 3 + 0] = wacc0 * 0.25f;
    influ[b * 3 + 1] = wacc1 * 0.25f;
    influ[b * 3 + 2] = wacc2 * 0.25f;
  }
}

// ---------- final heads (r0-verified): 28 length-512 dots per row ----------
__global__ __launch_bounds__(256) void heads_kernel(
    const u16* __restrict__ ah, const u16* __restrict__ oh,
    const float* __restrict__ Wap, const float* __restrict__ bap,
    const float* __restrict__ Wav, const float* __restrict__ bav,
    const float* __restrict__ Wop, const float* __restrict__ bop,
    const float* __restrict__ Wov, const float* __restrict__ bov,
    float* __restrict__ out) {
  __shared__ float sW[14336];
  for (int i = threadIdx.x; i < 14336; i += 256) {
    int s = i / 3584, rem = i - s * 3584;
    float v;
    if (s == 0) {
      v = (rem < 3072) ? Wap[rem] : Wav[rem - 3072];
    } else {
      int o = s - 1;
      v = (rem < 3072) ? Wop[o * 3072 + rem] : Wov[o * 512 + (rem - 3072)];
    }
    sW[i] = v;
  }
  __syncthreads();
  const int wave = threadIdx.x >> 6, lane = threadIdx.x & 63;
  const int kq = lane & 7, r = lane >> 3;
  const int b = blockIdx.x * 32 + wave * 8 + r;

  const u16* srcs[4] = {ah + (size_t)b * 512,
                        oh + (size_t)b * 512,
                        oh + (size_t)(Bsz + b) * 512,
                        oh + (size_t)(2 * Bsz + b) * 512};
  bf16x8 a[4][8];
#pragma unroll
  for (int s = 0; s < 4; s++)
#pragma unroll
    for (int c = 0; c < 8; c++)
      a[s][c] = *(const bf16x8*)(srcs[s] + c * 64 + kq * 8);

#pragma unroll
  for (int s = 0; s < 4; s++) {
#pragma unroll
    for (int p = 0; p < 7; p++) {
      const float* w = &sW[s * 3584 + p * 512 + kq * 8];
      float acc = 0.f;
#pragma unroll
      for (int c = 0; c < 8; c++) {
#pragma unroll
        for (int j = 0; j < 8; j++)
          acc += (float)a[s][c][j] * w[c * 64 + j];
      }
      acc += __shfl_xor(acc, 1, 64);
      acc += __shfl_xor(acc, 2, 64);
      acc += __shfl_xor(acc, 4, 64);
      if (kq == p) {
        if (s == 0) {
          if (p < 6) out[OUT_AP + b * 6 + p] = acc + bap[p];
          else       out[OUT_AV + b] = acc + bav[0];
        } else {
          int o = s - 1;
          if (p < 6) out[OUT_OP + b * 18 + o * 6 + p] = acc + bop[o * 6 + p];
          else       out[OUT_OV + b * 3 + o] = acc + bov[o];
        }
      }
    }
  }
}

extern "C" void kernel_launch(void* const* d_in, const int* in_sizes, int n_in,
                              void* d_out, int out_size, void* d_ws, size_t ws_size,
                              hipStream_t stream) {
  (void)in_sizes; (void)n_in; (void)out_size; (void)ws_size;
  const float* f     = (const float*)d_in[0];
  const float* W_al  = (const float*)d_in[1];
  const float* b_al  = (const float*)d_in[2];
  const float* W_in  = (const float*)d_in[3];
  const float* b_in  = (const float*)d_in[4];
  const float* W_out = (const float*)d_in[5];
  const float* b_out = (const float*)d_in[6];
  const float* W_ah  = (const float*)d_in[7];
  const float* b_ah  = (const float*)d_in[8];
  const float* W_ap  = (const float*)d_in[9];
  const float* b_ap  = (const float*)d_in[10];
  const float* W_av  = (const float*)d_in[11];
  const float* b_av  = (const float*)d_in[12];
  const float* W_ol  = (const float*)d_in[13];
  const float* b_ol  = (const float*)d_in[14];
  const float* W_oh  = (const float*)d_in[15];
  const float* b_oh  = (const float*)d_in[16];
  const float* W_op  = (const float*)d_in[17];
  const float* b_op  = (const float*)d_in[18];
  const float* W_ov  = (const float*)d_in[19];
  const float* b_ov  = (const float*)d_in[20];
  float* out = (float*)d_out;
  u16* ws = (u16*)d_ws;

  u16* feat  = ws + OFF_FEAT;
  u16* wal   = ws + OFF_WAL;    // [W_al ; W_ol] = W_lat (2048 x 1024)
  u16* win   = ws + OFF_WIN;
  u16* wahb  = ws + OFF_WAH;
  u16* woh   = ws + OFF_WOH;
  u16* lat   = ws + OFF_LAT;    // B x 2048
  u16* qb    = ws + OFF_Q;
  u16* kvb   = ws + OFF_KV;
  u16* att   = ws + OFF_ATT;
  u16* agh   = ws + OFF_AGH;
  u16* oph   = ws + OFF_OPH;
  u16* woutT = ws + OFF_WOUTT;
  u16* wcomb = ws + OFF_WCOMB;
  float* bahc = (float*)(ws + OFF_BAHC);
  float* zb   = (float*)(ws + OFF_ZB);

  // convert + woutT transpose + bahc (64 parallel blocks) + zb : one launch
  convert_all<<<12672, 256, 0, stream>>>(f, W_al, W_ol, W_in, W_out, W_ah,
                                         W_oh, ws, woutT, bahc, b_out, b_ah,
                                         zb);

  // lat = elu(feat @ W_lat^T + [b_al|b_ol]) : B x 2048
  gemm256<true><<<dim3(8, 32, 1), 512, 0, stream>>>(
      feat, wal, lat, b_al, b_ol, 512, 1024, 1024, 1024, 2048, 0, 0, 0, 0, 1.f);

  // q, kv(x3), opp_heads(x3), Wcomb : one exact-grid launch
  mega<<<2576, 256, 0, stream>>>(
      lat, win, woh, wahb, woutT, qb, kvb, oph, wcomb, b_in, b_oh, zb);

  attn_kernel<<<2048, 256, 0, stream>>>(qb, kvb, att, out + OUT_IN);

  // agent_head = elu([al | attn] @ [WahL ; Wcomb]^T + bahc)  (aout folded away)
  gemm_bt<64, true><<<dim3(8, 64), 256, 0, stream>>>(
      lat, att, wahb, wcomb, 512, 2048, 512, 1024, 512,
      agh, bahc, 1024, 512, 1.f);

  heads_kernel<<<256, 256, 0, stream>>>(agh, oph, W_ap, b_ap, W_av, b_av,
                                        W_op, b_op, W_ov, b_ov, out);
}